// Round 1
// baseline (298.994 us; speedup 1.0000x reference)
//
#include <hip/hip_runtime.h>
#include <math.h>

// Problem constants (from reference setup_inputs): B=64, Q=16, O=20, D=256,
// NUM_CAT=101, T=4096. T re-derived on host from out_size for safety.
constexpr int B_ = 64;
constexpr int Q_ = 16;
constexpr int O_ = 20;
constexpr int D_ = 256;

constexpr int ROWS_ = 256;   // t-rows per block

// ---------------------------------------------------------------------------
// Fused kernel: NO workspace. Each block recomputes belief[b] (16x256 = 16 KB)
// into LDS, then streams ROWS_ rows of the [B,T,D] expansion with float4
// stores. Belief recompute is redundant (T/ROWS_ = 16 blocks per batch) but
// costs ~2-3 us device-wide vs the 165 us workspace-poison fill it eliminates.
//
// Belief phase thread layout: tid = q*16 + k; thread computes softmax for its
// q (20 expf) and the 16 contiguous d-columns [k*16, k*16+16).
// Stream phase layout (unchanged from the verified kernel): 4 rows x 64 lanes
// x float4 per iteration; each wave writes one contiguous 1 KiB row.
// ---------------------------------------------------------------------------
__global__ __launch_bounds__(256) void fused_kernel(
    const float* __restrict__ logits,   // [B,Q,O]
    const float* __restrict__ emb,      // [NUM_CAT, D]
    const int*   __restrict__ cats,     // [B,O]
    const int*   __restrict__ cum,      // [B,Q]
    const int*   __restrict__ nq_arr,   // [B]
    float*       __restrict__ out,      // [B,T,D]
    int T)
{
    const int b   = blockIdx.y;
    const int t0  = blockIdx.x * ROWS_;
    const int tid = threadIdx.x;

    __shared__ float s_belief[Q_ * D_];   // 16 KB
    __shared__ float s_logit[Q_ * O_];    // 320 floats
    __shared__ int   s_cat[O_];

    // Stage logits[b] (320 floats) + cats[b] (20 ints).
    for (int i = tid; i < Q_ * O_; i += 256) s_logit[i] = logits[b * Q_ * O_ + i];
    if (tid < O_) s_cat[tid] = cats[b * O_ + tid];
    __syncthreads();

    // ---- belief[b,q,d] = tanh( sum_o softmax(logits[b,q,:])[o] * emb[cat[b,o],d] )
    {
        const int q  = tid >> 4;          // 0..15
        const int k  = tid & 15;          // 0..15
        const int d0 = k * 16;            // 16 contiguous d-columns per thread

        // Softmax weights for row q (redundant across the 16 k-threads; LDS
        // reads broadcast within each q-group).
        float m = -INFINITY;
        #pragma unroll
        for (int o = 0; o < O_; ++o) m = fmaxf(m, s_logit[q * O_ + o]);
        float w[O_];
        float sum = 0.f;
        #pragma unroll
        for (int o = 0; o < O_; ++o) {
            w[o] = expf(s_logit[q * O_ + o] - m);
            sum += w[o];
        }
        const float inv = 1.f / sum;

        float acc[16];
        #pragma unroll
        for (int j = 0; j < 16; ++j) acc[j] = 0.f;

        #pragma unroll
        for (int o = 0; o < O_; ++o) {
            const float wo = w[o] * inv;
            const float4* e = (const float4*)(emb + s_cat[o] * D_ + d0);
            #pragma unroll
            for (int j4 = 0; j4 < 4; ++j4) {
                const float4 v = e[j4];   // emb table is 103 KB -> L2-resident
                acc[j4 * 4 + 0] = fmaf(wo, v.x, acc[j4 * 4 + 0]);
                acc[j4 * 4 + 1] = fmaf(wo, v.y, acc[j4 * 4 + 1]);
                acc[j4 * 4 + 2] = fmaf(wo, v.z, acc[j4 * 4 + 2]);
                acc[j4 * 4 + 3] = fmaf(wo, v.w, acc[j4 * 4 + 3]);
            }
        }

        #pragma unroll
        for (int j = 0; j < 16; ++j)
            s_belief[q * D_ + d0 + j] = tanhf(acc[j]);
    }

    // Per-thread question boundaries (registers, fully unrolled).
    const int nq = nq_arr[b];
    int bnd[Q_ - 1];
    #pragma unroll
    for (int j = 1; j < Q_; ++j)
        bnd[j - 1] = (j <= nq - 1) ? (cum[b * Q_ + j] - 1) : 0x7fffffff;

    __syncthreads();

    // ---- expansion: out[b,t,:] = (qi < nq-1) ? belief[b,qi,:] : 0
    const int col  = (tid & 63) * 4;    // float4 column offset within row
    const int rsub = tid >> 6;          // 0..3: row within the 4-row group
    float* const out_b = out + (size_t)b * T * (size_t)D_;

    #pragma unroll 4
    for (int it = 0; it < ROWS_ / 4; ++it) {
        const int t = t0 + it * 4 + rsub;
        if (t >= T) break;

        int qi = 0;
        #pragma unroll
        for (int j = 0; j < Q_ - 1; ++j) qi += (t >= bnd[j]) ? 1 : 0;

        float4 v = make_float4(0.f, 0.f, 0.f, 0.f);
        if (qi < nq - 1) {
            const int qc = qi < (Q_ - 1) ? qi : (Q_ - 1);
            v = *(const float4*)(s_belief + qc * D_ + col);
        }
        *(float4*)(out_b + (size_t)t * D_ + col) = v;
    }
}

extern "C" void kernel_launch(void* const* d_in, const int* in_sizes, int n_in,
                              void* d_out, int out_size, void* d_ws, size_t ws_size,
                              hipStream_t stream)
{
    const float* logits = (const float*)d_in[0];   // [B,Q,O] fp32
    const float* emb    = (const float*)d_in[1];   // [101,D] fp32
    const int*   cats   = (const int*)d_in[2];     // [B,O] int32
    const int*   cum    = (const int*)d_in[3];     // [B,Q] int32
    const int*   nq     = (const int*)d_in[4];     // [B] int32
    // d_in[5] = max_dln scalar; T derived from out_size instead.

    float* out = (float*)d_out;
    const int T = out_size / (B_ * D_);            // 4096

    // NOTE: d_ws intentionally unused — avoiding the 1 GiB workspace poison
    // fill (~165 us) that dominated the timed graph.
    (void)d_ws; (void)ws_size;

    dim3 grid((T + ROWS_ - 1) / ROWS_, B_);
    fused_kernel<<<grid, 256, 0, stream>>>(logits, emb, cats, cum, nq, out, T);
}

// Round 3
// 286.126 us; speedup vs baseline: 1.0450x; 1.0450x over previous
//
#include <hip/hip_runtime.h>
#include <math.h>

// Problem constants (from reference setup_inputs): B=64, Q=16, O=20, D=256,
// NUM_CAT=101, T=4096. T re-derived on host from out_size for safety.
constexpr int B_ = 64;
constexpr int Q_ = 16;
constexpr int O_ = 20;
constexpr int D_ = 256;

typedef float vf4 __attribute__((ext_vector_type(4)));

// ---------------------------------------------------------------------------
// Kernel 1: belief[b,q,d] = tanh( sum_o softmax(logits[b,q,:])[o] *
//                                 emb[cat[b,o], d] )
// Grid: B*Q blocks, D threads. ~4 us total. (Fusing this into the expand
// kernel was tried in round 1 and regressed +28 us: the per-block recompute
// serializes 36 transcendentals/thread ahead of the streaming phase.)
// ---------------------------------------------------------------------------
__global__ __launch_bounds__(D_) void belief_kernel(
    const float* __restrict__ logits,   // [B,Q,O]
    const float* __restrict__ emb,      // [NUM_CAT, D]
    const int*   __restrict__ cats,     // [B,O]
    float*       __restrict__ belief)   // [B,Q,D] (workspace)
{
    const int bq = blockIdx.x;          // b*Q + q
    const int b  = bq >> 4;             // Q_ == 16
    const int d  = threadIdx.x;         // 0..255

    __shared__ float s_logit[O_];
    __shared__ int   s_cat[O_];
    if (d < O_) {
        s_logit[d] = logits[bq * O_ + d];
        s_cat[d]   = cats[b * O_ + d];
    }
    __syncthreads();

    float m = -INFINITY;
    #pragma unroll
    for (int o = 0; o < O_; ++o) m = fmaxf(m, s_logit[o]);
    float w[O_];
    float sum = 0.f;
    #pragma unroll
    for (int o = 0; o < O_; ++o) { w[o] = expf(s_logit[o] - m); sum += w[o]; }
    const float inv = 1.f / sum;

    float acc = 0.f;
    #pragma unroll
    for (int o = 0; o < O_; ++o)
        acc = fmaf(w[o] * inv, emb[s_cat[o] * D_ + d], acc);

    belief[bq * D_ + d] = tanhf(acc);
}

// ---------------------------------------------------------------------------
// Kernel 2: expansion. out[b,t,:] = (qi(t) < nq-1) ? belief[b, qi(t), :] : 0
// ROWS_=128: grid (32, 64) = 2048 blocks = 8 blocks/CU = 32 waves/CU (max
// occupancy; LDS 16 KB x 8 = 128 KB <= 160 KB).
// Each wave owns whole rows (t uniform across the wave), so qi is
// wave-uniform; it changes at most 15 times over 4096 rows -> cache the
// loaded float4 and only touch LDS when the source row changes.
// Blocks entirely past the last question boundary skip staging and emit
// pure zero-fill. Stores are nontemporal (output is never re-read).
// ---------------------------------------------------------------------------
constexpr int ROWS_ = 128;   // t-rows per block

__global__ __launch_bounds__(256) void expand_kernel(
    const float* __restrict__ belief,   // [B,Q,D]
    const int*   __restrict__ cum,      // [B,Q]
    const int*   __restrict__ nq_arr,   // [B]
    float*       __restrict__ out,      // [B,T,D]
    int T)
{
    const int b   = blockIdx.y;
    const int t0  = blockIdx.x * ROWS_;
    const int tid = threadIdx.x;

    __shared__ float s_belief[Q_ * D_];   // 16 KB

    const int nq = nq_arr[b];             // nq >= 2
    // Tokens t >= limit have qi >= nq-1 -> invalid -> zero output.
    const int limit = cum[b * Q_ + (nq - 1)] - 1;

    const int col  = (tid & 63) * 4;      // float4 column offset within row
    const int rsub = tid >> 6;            // 0..3: row within the 4-row group
    float* outp = out + ((size_t)b * T + t0 + rsub) * (size_t)D_ + col;

    if (t0 >= limit) {
        // Whole block invalid (block-uniform branch): pure streaming
        // zero-fill, no staging, no barrier.
        const vf4 z = {0.f, 0.f, 0.f, 0.f};
        #pragma unroll 4
        for (int it = 0; it < ROWS_ / 4; ++it) {
            const int t = t0 + it * 4 + rsub;
            if (t >= T) break;
            __builtin_nontemporal_store(z, (vf4*)outp);
            outp += 4 * D_;
        }
        return;
    }

    // Stage belief[b]: 4096 floats = 1024 float4, 256 threads x 4.
    {
        const vf4* src = (const vf4*)(belief + (size_t)b * Q_ * D_);
        vf4*       dst = (vf4*)s_belief;
        #pragma unroll
        for (int i = 0; i < (Q_ * D_ / 4) / 256; ++i)
            dst[tid + i * 256] = src[tid + i * 256];
    }

    // Question boundaries in registers (fully unrolled).
    int bnd[Q_ - 1];
    #pragma unroll
    for (int j = 1; j < Q_; ++j)
        bnd[j - 1] = (j <= nq - 1) ? (cum[b * Q_ + j] - 1) : 0x7fffffff;

    __syncthreads();

    int prev_r = -2;                      // cached source row (-1 == zeros)
    vf4 v = {0.f, 0.f, 0.f, 0.f};

    for (int it = 0; it < ROWS_ / 4; ++it) {
        const int t = t0 + it * 4 + rsub;
        if (t >= T) break;

        int qi = 0;
        #pragma unroll
        for (int j = 0; j < Q_ - 1; ++j) qi += (t >= bnd[j]) ? 1 : 0;
        const int r = (qi < nq - 1) ? qi : -1;   // qi <= 15 by construction

        if (r != prev_r) {                // wave-uniform; fires <= 15 times total
            if (r >= 0) v = *(const vf4*)(s_belief + r * D_ + col);
            else        v = (vf4){0.f, 0.f, 0.f, 0.f};
            prev_r = r;
        }
        __builtin_nontemporal_store(v, (vf4*)outp);
        outp += 4 * D_;
    }
}

extern "C" void kernel_launch(void* const* d_in, const int* in_sizes, int n_in,
                              void* d_out, int out_size, void* d_ws, size_t ws_size,
                              hipStream_t stream)
{
    const float* logits = (const float*)d_in[0];   // [B,Q,O] fp32
    const float* emb    = (const float*)d_in[1];   // [101,D] fp32
    const int*   cats   = (const int*)d_in[2];     // [B,O] int32
    const int*   cum    = (const int*)d_in[3];     // [B,Q] int32
    const int*   nq     = (const int*)d_in[4];     // [B] int32
    // d_in[5] = max_dln scalar; T derived from out_size instead.

    float* out    = (float*)d_out;
    float* belief = (float*)d_ws;                  // B*Q*D floats = 1 MiB
    const int T = out_size / (B_ * D_);            // 4096

    belief_kernel<<<B_ * Q_, D_, 0, stream>>>(logits, emb, cats, belief);

    dim3 grid((T + ROWS_ - 1) / ROWS_, B_);
    expand_kernel<<<grid, 256, 0, stream>>>(belief, cum, nq, out, T);
}

// Round 4
// 270.821 us; speedup vs baseline: 1.1040x; 1.0565x over previous
//
#include <hip/hip_runtime.h>
#include <math.h>

// Problem constants (from reference setup_inputs): B=64, Q=16, O=20, D=256,
// NUM_CAT=101, T=4096. T re-derived on host from out_size for safety.
constexpr int B_ = 64;
constexpr int Q_ = 16;
constexpr int O_ = 20;
constexpr int D_ = 256;

typedef float vf4 __attribute__((ext_vector_type(4)));

// ---------------------------------------------------------------------------
// Kernel 1: belief[b,q,d] = tanh( sum_o softmax(logits[b,q,:])[o] *
//                                 emb[cat[b,o], d] )
// Grid: B*Q blocks, D threads. ~4 us total. (Fusing into expand regressed
// +28 us in round 1; keep two kernels.)
// ---------------------------------------------------------------------------
__global__ __launch_bounds__(D_) void belief_kernel(
    const float* __restrict__ logits,   // [B,Q,O]
    const float* __restrict__ emb,      // [NUM_CAT, D]
    const int*   __restrict__ cats,     // [B,O]
    float*       __restrict__ belief)   // [B,Q,D] (workspace)
{
    const int bq = blockIdx.x;          // b*Q + q
    const int b  = bq >> 4;             // Q_ == 16
    const int d  = threadIdx.x;         // 0..255

    __shared__ float s_logit[O_];
    __shared__ int   s_cat[O_];
    if (d < O_) {
        s_logit[d] = logits[bq * O_ + d];
        s_cat[d]   = cats[b * O_ + d];
    }
    __syncthreads();

    float m = -INFINITY;
    #pragma unroll
    for (int o = 0; o < O_; ++o) m = fmaxf(m, s_logit[o]);
    float w[O_];
    float sum = 0.f;
    #pragma unroll
    for (int o = 0; o < O_; ++o) { w[o] = expf(s_logit[o] - m); sum += w[o]; }
    const float inv = 1.f / sum;

    float acc = 0.f;
    #pragma unroll
    for (int o = 0; o < O_; ++o)
        acc = fmaf(w[o] * inv, emb[s_cat[o] * D_ + d], acc);

    belief[bq * D_ + d] = tanhf(acc);
}

// ---------------------------------------------------------------------------
// Kernel 2: expansion. out[b,t,:] = (qi(t) < nq-1) ? belief[b, qi(t), :] : 0
//
// Round-0 skeleton (ROWS_=256, plain float4 stores, unconditional staging —
// measured 270.9 total; nt stores + ROWS_=128 regressed to 286). ONE change:
// qi(t) is monotone in t, so a block's 256 rows form <= 16 constant-value
// segments. Walk segments: one LDS read per segment, then a tight store-only
// inner loop (pure pointer-increment dwordx4 stream). All bounds are
// wave-uniform (rsub is per-wave, segment bounds block-uniform) -> zero
// divergence. Boundaries live in LDS because the walk indexes them
// dynamically (register array would spill to scratch).
// ---------------------------------------------------------------------------
constexpr int ROWS_ = 256;   // t-rows per block

__global__ __launch_bounds__(256) void expand_kernel(
    const float* __restrict__ belief,   // [B,Q,D]
    const int*   __restrict__ cum,      // [B,Q]
    const int*   __restrict__ nq_arr,   // [B]
    float*       __restrict__ out,      // [B,T,D]
    int T)
{
    const int b   = blockIdx.y;
    const int t0  = blockIdx.x * ROWS_;
    const int tid = threadIdx.x;

    __shared__ float s_belief[Q_ * D_];   // 16 KB
    __shared__ int   s_bnd[Q_ - 1];

    // Stage belief[b]: 4096 floats = 1024 float4, 256 threads x 4.
    {
        const vf4* src = (const vf4*)(belief + (size_t)b * Q_ * D_);
        vf4*       dst = (vf4*)s_belief;
        #pragma unroll
        for (int i = 0; i < (Q_ * D_ / 4) / 256; ++i)
            dst[tid + i * 256] = src[tid + i * 256];
    }

    const int nq = nq_arr[b];             // nq >= 2
    if (tid < Q_ - 1) {
        const int j = tid + 1;            // boundary j: end of question j-1
        s_bnd[tid] = (j <= nq - 1) ? (cum[b * Q_ + j] - 1) : 0x7fffffff;
    }
    __syncthreads();

    const int col  = (tid & 63) * 4;      // float4 column offset within row
    const int rsub = tid >> 6;            // 0..3: row within the 4-row group
    float* const out_b = out + (size_t)b * T * (size_t)D_ + col;

    const int blk_end = (t0 + ROWS_ < T) ? (t0 + ROWS_) : T;

    // Question index owning row t0: # boundaries <= t0 (broadcast LDS reads).
    int k = 0;
    #pragma unroll
    for (int j = 0; j < Q_ - 1; ++j) k += (t0 >= s_bnd[j]) ? 1 : 0;

    // Segment walk. Terminates: for k >= nq-1, s_bnd[k] == INT_MAX so
    // seg_e == blk_end. At most ~16 iterations, all block-uniform.
    int seg_s = t0;
    while (seg_s < blk_end) {
        const int bk    = (k < Q_ - 1) ? s_bnd[k] : 0x7fffffff;
        const int seg_e = (bk < blk_end) ? bk : blk_end;

        vf4 v = {0.f, 0.f, 0.f, 0.f};
        if (k < nq - 1)                   // block-uniform
            v = *(const vf4*)(s_belief + k * D_ + col);

        // This thread's rows t ≡ rsub (mod 4) in [seg_s, seg_e).
        // ((rsub - seg_s) & 3) == (rsub - seg_s) mod 4 (two's complement).
        for (int t = seg_s + ((rsub - seg_s) & 3); t < seg_e; t += 4)
            *(vf4*)(out_b + (size_t)t * D_) = v;

        seg_s = seg_e;
        ++k;
    }
}

extern "C" void kernel_launch(void* const* d_in, const int* in_sizes, int n_in,
                              void* d_out, int out_size, void* d_ws, size_t ws_size,
                              hipStream_t stream)
{
    const float* logits = (const float*)d_in[0];   // [B,Q,O] fp32
    const float* emb    = (const float*)d_in[1];   // [101,D] fp32
    const int*   cats   = (const int*)d_in[2];     // [B,O] int32
    const int*   cum    = (const int*)d_in[3];     // [B,Q] int32
    const int*   nq     = (const int*)d_in[4];     // [B] int32
    // d_in[5] = max_dln scalar; T derived from out_size instead.

    float* out    = (float*)d_out;
    float* belief = (float*)d_ws;                  // B*Q*D floats = 1 MiB
    const int T = out_size / (B_ * D_);            // 4096

    belief_kernel<<<B_ * Q_, D_, 0, stream>>>(logits, emb, cats, belief);

    dim3 grid((T + ROWS_ - 1) / ROWS_, B_);
    expand_kernel<<<grid, 256, 0, stream>>>(belief, cum, nq, out, T);
}